// Round 8
// baseline (261.189 us; speedup 1.0000x reference)
//
#include <hip/hip_runtime.h>
#include <math.h>

#define NBATCH 4096
#define TNUM   128
#define NOBSC  10
#define MAXIT  30

// ws layout (floats)
#define WS_MX   0      // 16x16
#define WS_MY   256    // 16x16
#define WS_MGX  512    // 16x16  (Mx*Gx)
#define WS_MGY  768    // 16x16  (My*Gy)
#define WS_NX   1024   // 16x8
#define WS_NY   1152   // 16x9
#define WS_NX0  1296   // 16x8
#define WS_NY0  1424   // 16x9
// total 1568 floats

#define RSTRIDE 132    // padded row stride for reduction buffer (33 x 16B)

typedef float f32x2 __attribute__((ext_vector_type(2)));
union F4 { float4 v; float f[4]; };

__device__ __forceinline__ f32x2 pfma(f32x2 a, f32x2 b, f32x2 c) {
  return __builtin_elementwise_fma(a, b, c);
}

// ---------------- setup kernel: build + invert KKT matrices (fp64 GJ) -------
__global__ __launch_bounds__(64) void planner_setup(
    const float* __restrict__ P, const float* __restrict__ Pd, const float* __restrict__ Pdd,
    float* __restrict__ ws)
{
  const int mid = blockIdx.x;   // 0: (cost_sm,Ax)->Nx0  1: (cost_sm,Ay)->Ny0
                                // 2: (cost_x,Ax)->Mx,Nx,MGx 3: (cost_y,Ay)->My,Ny,MGy
  const int tid = threadIdx.x;
  __shared__ double C[16][16];
  __shared__ double G[16][16];
  __shared__ double Ae[9][16];
  __shared__ double aug[25][50];
  __shared__ int pivs;

  const bool isY = (mid & 1);
  const int  m   = isY ? 9 : 8;
  const int  n   = 16 + m;
  const int  w   = 2 * n;

  // Gram matrices + cost matrix
  for (int e = tid; e < 256; e += 64) {
    const int j = e >> 4, k = e & 15;
    double gdd = 0.0, gd = 0.0, g0 = 0.0;
    for (int t = 0; t < TNUM; ++t) {
      gdd += (double)Pdd[t*16+j] * (double)Pdd[t*16+k];
      gd  += (double)Pd [t*16+j] * (double)Pd [t*16+k];
      g0  += (double)P  [t*16+j] * (double)P  [t*16+k];
    }
    const double cs = 100.0 * (gdd + ((j == k) ? 0.1 : 0.0));   // cost_sm
    const double g  = gdd + gd + (isY ? 12.0 : 10.0) * g0;      // Gx or Gy
    G[j][k] = g;
    C[j][k] = (mid >= 2) ? (cs + g) : cs;
  }
  if (tid < 16) {
    const int j = tid;
    Ae[0][j] = (double)P  [0*16+j];
    Ae[1][j] = (double)Pd [0*16+j];
    Ae[2][j] = (double)Pdd[0*16+j];
    if (!isY) {
      Ae[3][j] = (double)Pd[127*16+j];
      for (int r = 4; r < 8; ++r) Ae[r][j] = (j == r) ? 1.0 : 0.0;
    } else {
      Ae[3][j] = (double)P [127*16+j];
      Ae[4][j] = (double)Pd[127*16+j];
      for (int r = 5; r < 9; ++r) Ae[r][j] = (j == (r-1)) ? 1.0 : 0.0;
    }
  }
  __syncthreads();

  // build augmented [KKT | I]
  for (int e = tid; e < n * w; e += 64) {
    const int r = e / w, c = e % w;
    double val;
    if (c < n) {
      if (r < 16) val = (c < 16) ? C[r][c] : Ae[c-16][r];
      else        val = (c < 16) ? Ae[r-16][c] : 0.0;
    } else {
      val = ((c - n) == r) ? 1.0 : 0.0;
    }
    aug[r][c] = val;
  }
  __syncthreads();

  // Gauss-Jordan with partial pivoting
  for (int k = 0; k < n; ++k) {
    if (tid == 0) {
      int p = k; double best = fabs(aug[k][k]);
      for (int r = k+1; r < n; ++r) { double a = fabs(aug[r][k]); if (a > best) { best = a; p = r; } }
      pivs = p;
    }
    __syncthreads();
    const int p = pivs;
    if (p != k) {
      for (int c = tid; c < w; c += 64) { double t = aug[k][c]; aug[k][c] = aug[p][c]; aug[p][c] = t; }
    }
    __syncthreads();
    const double ipiv = 1.0 / aug[k][k];
    for (int c = tid; c < w; c += 64) aug[k][c] *= ipiv;
    __syncthreads();
    for (int r = tid; r < n; r += 64) {
      if (r != k) {
        const double f = aug[r][k];
        for (int c = k; c < w; ++c) aug[r][c] -= f * aug[k][c];
      }
    }
    __syncthreads();
  }

  // write sub-blocks of the inverse (cols n.. of aug)
  if (mid == 0) {
    for (int e = tid; e < 16*8; e += 64) ws[WS_NX0 + e] = (float)aug[e >> 3][n + 16 + (e & 7)];
  } else if (mid == 1) {
    for (int e = tid; e < 16*9; e += 64) ws[WS_NY0 + e] = (float)aug[e / 9][n + 16 + (e % 9)];
  } else if (mid == 2) {
    for (int e = tid; e < 256;  e += 64) ws[WS_MX + e] = (float)aug[e >> 4][n + (e & 15)];
    for (int e = tid; e < 16*8; e += 64) ws[WS_NX + e] = (float)aug[e >> 3][n + 16 + (e & 7)];
  } else {
    for (int e = tid; e < 256;  e += 64) ws[WS_MY + e] = (float)aug[e >> 4][n + (e & 15)];
    for (int e = tid; e < 16*9; e += 64) ws[WS_NY + e] = (float)aug[e / 9][n + 16 + (e % 9)];
  }

  // MG = M * G  (fp64), for the fused per-iteration solve
  if (mid >= 2) {
    for (int e = tid; e < 256; e += 64) {
      const int j = e >> 4, k = e & 15;
      double s = 0.0;
      for (int mm = 0; mm < 16; ++mm) s += aug[j][n + mm] * G[mm][k];
      ws[(mid == 2 ? WS_MGX : WS_MGY) + e] = (float)s;
    }
  }
}

// ------- main kernel: 128 threads, TWO batch elements pipelined per block ----
__global__ __launch_bounds__(128, 2) void planner_main(
    const float* __restrict__ P, const float* __restrict__ Pd, const float* __restrict__ Pdd,
    const float* __restrict__ init_state, const float* __restrict__ fin_state,
    const float* __restrict__ cobs, const float* __restrict__ vobs,
    const float* __restrict__ yub_g, const float* __restrict__ ylb_g,
    const float* __restrict__ lamx_g, const float* __restrict__ lamy_g,
    const float* __restrict__ cxp_g, const float* __restrict__ cyp_g,
    const float* __restrict__ ws, float* __restrict__ out)
{
  const int b0   = blockIdx.x * 2;
  const int b1   = b0 + 1;
  const int tid  = threadIdx.x;
  const int lane = tid & 63;
  const int wv   = tid >> 6;
  const int r32  = lane & 31;          // reduction row owned (dup over lane>=32)
  const int rr   = tid & 15;           // solve row
  const int side = (tid >> 4) & 1;     // 0 = x-side, 1 = y-side

  __shared__ alignas(16) float redA[32*RSTRIDE];
  __shared__ alignas(16) float redB[32*RSTRIDE];
  __shared__ alignas(16) float cLwA[2][32];
  __shared__ alignas(16) float cLwB[2][32];
  __shared__ alignas(16) float hLwA[2][32];
  __shared__ alignas(16) float hLwB[2][32];
  __shared__ float pLA[2][32];
  __shared__ float pLB[2][32];

  // basis rows for this lane's timestep t = tid (SHARED between A and B)
  f32x2 Pr2[8], Pdr2[8], Pddr2[8];
  #pragma unroll
  for (int q = 0; q < 4; ++q) {
    F4 a, bb, cc;
    a.v  = *reinterpret_cast<const float4*>(P   + tid*16 + 4*q);
    bb.v = *reinterpret_cast<const float4*>(Pd  + tid*16 + 4*q);
    cc.v = *reinterpret_cast<const float4*>(Pdd + tid*16 + 4*q);
    Pr2  [2*q+0] = f32x2{a.f[0],  a.f[1]};  Pr2  [2*q+1] = f32x2{a.f[2],  a.f[3]};
    Pdr2 [2*q+0] = f32x2{bb.f[0], bb.f[1]}; Pdr2 [2*q+1] = f32x2{bb.f[2], bb.f[3]};
    Pddr2[2*q+0] = f32x2{cc.f[0], cc.f[1]}; Pddr2[2*q+1] = f32x2{cc.f[2], cc.f[3]};
  }

  // pre-scaled obstacle trajectories, per problem
  f32x2 xot2A[5], yot2A[5], xot2B[5], yot2B[5];
  {
    const float tt = (float)tid * (10.0f/127.0f);
    #pragma unroll
    for (int o5 = 0; o5 < 5; ++o5) {
      const int o = 2*o5;
      xot2A[o5] = f32x2{3.2f * fmaf(vobs[b0*20+o],    tt, cobs[b0*20+o]),
                        3.2f * fmaf(vobs[b0*20+o+1],  tt, cobs[b0*20+o+1])};
      yot2A[o5] = f32x2{6.0f * fmaf(vobs[b0*20+10+o], tt, cobs[b0*20+10+o]),
                        6.0f * fmaf(vobs[b0*20+11+o], tt, cobs[b0*20+11+o])};
      xot2B[o5] = f32x2{3.2f * fmaf(vobs[b1*20+o],    tt, cobs[b1*20+o]),
                        3.2f * fmaf(vobs[b1*20+o+1],  tt, cobs[b1*20+o+1])};
      yot2B[o5] = f32x2{6.0f * fmaf(vobs[b1*20+10+o], tt, cobs[b1*20+10+o]),
                        6.0f * fmaf(vobs[b1*20+11+o], tt, cobs[b1*20+11+o])};
    }
  }
  const float yubA = yub_g[b0], ylbA = ylb_g[b0];
  const float yubB = yub_g[b1], ylbB = ylb_g[b1];

  // lambda carries for this lane's reduction row
  float lamA = (r32 < 16) ? lamx_g[b0*16 + r32] : lamy_g[b0*16 + (r32 - 16)];
  float lamB = (r32 < 16) ? lamx_g[b1*16 + r32] : lamy_g[b1*16 + (r32 - 16)];

  // per-lane solve-row setup for both problems
  float constvA, mycA, constvB, mycB;
  {
    const int nstr = side ? 9 : 8;
    const float* Np  = ws + (side ? WS_NY  : WS_NX ) + rr*nstr;
    const float* N0p = ws + (side ? WS_NY0 : WS_NX0) + rr*nstr;

    float beq[9];
    // ---- problem A ----
    {
      const float vi  = init_state[b0*4+2];
      const float psi = init_state[b0*4+3];
      if (side == 0) {
        beq[0] = init_state[b0*4+0];
        beq[1] = vi * cosf(psi);
        beq[2] = 0.f;
        beq[3] = fin_state[b0*3+0];
        #pragma unroll
        for (int i2 = 0; i2 < 4; ++i2) beq[4+i2] = cxp_g[b0*4+i2];
        beq[8] = 0.f;
      } else {
        beq[0] = init_state[b0*4+1];
        beq[1] = vi * sinf(psi);
        beq[2] = 0.f;
        beq[3] = fin_state[b0*3+1];
        beq[4] = 0.f;
        #pragma unroll
        for (int i2 = 0; i2 < 4; ++i2) beq[5+i2] = cyp_g[b0*4+i2];
      }
      float cv = 0.f, c0 = 0.f;
      #pragma unroll
      for (int mm = 0; mm < 9; ++mm) {
        const float bm = beq[mm];
        cv = fmaf(Np[mm],  bm, cv);
        c0 = fmaf(N0p[mm], bm, c0);
      }
      constvA = cv;  mycA = c0;
      if (lane < 32) cLwA[wv][lane] = c0;
    }
    // ---- problem B ----
    {
      const float vi  = init_state[b1*4+2];
      const float psi = init_state[b1*4+3];
      if (side == 0) {
        beq[0] = init_state[b1*4+0];
        beq[1] = vi * cosf(psi);
        beq[2] = 0.f;
        beq[3] = fin_state[b1*3+0];
        #pragma unroll
        for (int i2 = 0; i2 < 4; ++i2) beq[4+i2] = cxp_g[b1*4+i2];
        beq[8] = 0.f;
      } else {
        beq[0] = init_state[b1*4+1];
        beq[1] = vi * sinf(psi);
        beq[2] = 0.f;
        beq[3] = fin_state[b1*3+1];
        beq[4] = 0.f;
        #pragma unroll
        for (int i2 = 0; i2 < 4; ++i2) beq[5+i2] = cyp_g[b1*4+i2];
      }
      float cv = 0.f, c0 = 0.f;
      #pragma unroll
      for (int mm = 0; mm < 9; ++mm) {
        const float bm = beq[mm];
        cv = fmaf(Np[mm],  bm, cv);
        c0 = fmaf(N0p[mm], bm, c0);
      }
      constvB = cv;  mycB = c0;
      if (lane < 32) cLwB[wv][lane] = c0;
    }
  }

  const float* Mrow  = ws + (side ? WS_MY  : WS_MX ) + rr*16;
  const float* MGrow = ws + (side ? WS_MGY : WS_MGX) + rr*16;

  #pragma unroll 1
  for (int it = 0; it < MAXIT; ++it) {
    // ---- forward matvecs, A and B interleaved (independent chains) ----
    f32x2 xvA{}, yvA{}, xdvA{}, ydvA{}, xddvA{}, yddvA{};
    f32x2 xvB{}, yvB{}, xdvB{}, ydvB{}, xddvB{}, yddvB{};
    #pragma unroll
    for (int q = 0; q < 4; ++q) {
      F4 cxa, cya, cxb, cyb;
      cxa.v = *reinterpret_cast<const float4*>(&cLwA[wv][4*q]);
      cya.v = *reinterpret_cast<const float4*>(&cLwA[wv][16 + 4*q]);
      cxb.v = *reinterpret_cast<const float4*>(&cLwB[wv][4*q]);
      cyb.v = *reinterpret_cast<const float4*>(&cLwB[wv][16 + 4*q]);
      const f32x2 cA01 = f32x2{cxa.f[0], cxa.f[1]}, cA23 = f32x2{cxa.f[2], cxa.f[3]};
      const f32x2 dA01 = f32x2{cya.f[0], cya.f[1]}, dA23 = f32x2{cya.f[2], cya.f[3]};
      const f32x2 cB01 = f32x2{cxb.f[0], cxb.f[1]}, cB23 = f32x2{cxb.f[2], cxb.f[3]};
      const f32x2 dB01 = f32x2{cyb.f[0], cyb.f[1]}, dB23 = f32x2{cyb.f[2], cyb.f[3]};
      xvA   = pfma(Pr2  [2*q], cA01, xvA);   xvA   = pfma(Pr2  [2*q+1], cA23, xvA);
      yvA   = pfma(Pr2  [2*q], dA01, yvA);   yvA   = pfma(Pr2  [2*q+1], dA23, yvA);
      xdvA  = pfma(Pdr2 [2*q], cA01, xdvA);  xdvA  = pfma(Pdr2 [2*q+1], cA23, xdvA);
      ydvA  = pfma(Pdr2 [2*q], dA01, ydvA);  ydvA  = pfma(Pdr2 [2*q+1], dA23, ydvA);
      xddvA = pfma(Pddr2[2*q], cA01, xddvA); xddvA = pfma(Pddr2[2*q+1], cA23, xddvA);
      yddvA = pfma(Pddr2[2*q], dA01, yddvA); yddvA = pfma(Pddr2[2*q+1], dA23, yddvA);
      xvB   = pfma(Pr2  [2*q], cB01, xvB);   xvB   = pfma(Pr2  [2*q+1], cB23, xvB);
      yvB   = pfma(Pr2  [2*q], dB01, yvB);   yvB   = pfma(Pr2  [2*q+1], dB23, yvB);
      xdvB  = pfma(Pdr2 [2*q], cB01, xdvB);  xdvB  = pfma(Pdr2 [2*q+1], cB23, xdvB);
      ydvB  = pfma(Pdr2 [2*q], dB01, ydvB);  ydvB  = pfma(Pdr2 [2*q+1], dB23, ydvB);
      xddvB = pfma(Pddr2[2*q], cB01, xddvB); xddvB = pfma(Pddr2[2*q+1], cB23, xddvB);
      yddvB = pfma(Pddr2[2*q], dB01, yddvB); yddvB = pfma(Pddr2[2*q+1], dB23, yddvB);
    }
    const float xA   = xvA.x   + xvA.y,   yA   = yvA.x   + yvA.y;
    const float xdA  = xdvA.x  + xdvA.y,  ydA  = ydvA.x  + ydvA.y;
    const float xddA = xddvA.x + xddvA.y, yddA = yddvA.x + yddvA.y;
    const float xB   = xvB.x   + xvB.y,   yB   = yvB.x   + yvB.y;
    const float xdB  = xdvB.x  + xdvB.y,  ydB  = ydvB.x  + ydvB.y;
    const float xddB = xddvB.x + xddvB.y, yddB = yddvB.x + yddvB.y;

    // ---- projections ----
    const float riaA = rsqrtf(fmaxf(fmaf(xddA, xddA, yddA*yddA), 1e-36f));
    const float ga1A = 1.0f - fminf(1.0f, 18.0f * riaA);
    const float rivA = rsqrtf(fmaxf(fmaf(xdA, xdA, ydA*ydA), 1e-36f));
    const float gv1A = 1.0f - fminf(fmaxf(1.0f, 0.1f*rivA), 30.0f*rivA);
    const float riaB = rsqrtf(fmaxf(fmaf(xddB, xddB, yddB*yddB), 1e-36f));
    const float ga1B = 1.0f - fminf(1.0f, 18.0f * riaB);
    const float rivB = rsqrtf(fmaxf(fmaf(xdB, xdB, ydB*ydB), 1e-36f));
    const float gv1B = 1.0f - fminf(fmaxf(1.0f, 0.1f*rivB), 30.0f*rivB);

    // ---- obstacles ----
    f32x2 Sx2A{}, Sy2A{}, Sx2B{}, Sy2B{};
    {
      const float t32A = 3.2f * xA, t6A = 6.0f * yA;
      const float t32B = 3.2f * xB, t6B = 6.0f * yB;
      const f32x2 xbA = f32x2{t32A, t32A}, ybA = f32x2{t6A, t6A};
      const f32x2 xbB = f32x2{t32B, t32B}, ybB = f32x2{t6B, t6B};
      #pragma unroll
      for (int o5 = 0; o5 < 5; ++o5) {
        const f32x2 bwA = xbA - xot2A[o5];
        const f32x2 awA = ybA - yot2A[o5];
        const f32x2 bwB = xbB - xot2B[o5];
        const f32x2 awB = ybB - yot2B[o5];
        f32x2 r2A = pfma(bwA, bwA, awA*awA);
        f32x2 r2B = pfma(bwB, bwB, awB*awB);
        const float e0A = fmaxf(fmaf(19.2f, rsqrtf(fmaxf(r2A.x, 1e-36f)), -1.0f), 0.f);
        const float e1A = fmaxf(fmaf(19.2f, rsqrtf(fmaxf(r2A.y, 1e-36f)), -1.0f), 0.f);
        const float e0B = fmaxf(fmaf(19.2f, rsqrtf(fmaxf(r2B.x, 1e-36f)), -1.0f), 0.f);
        const float e1B = fmaxf(fmaf(19.2f, rsqrtf(fmaxf(r2B.y, 1e-36f)), -1.0f), 0.f);
        const f32x2 eeA = f32x2{e0A, e1A};
        const f32x2 eeB = f32x2{e0B, e1B};
        Sx2A = pfma(eeA, bwA, Sx2A);
        Sy2A = pfma(eeA, awA, Sy2A);
        Sx2B = pfma(eeB, bwB, Sx2B);
        Sy2B = pfma(eeB, awB, Sy2B);
      }
    }
    const float SxpA = Sx2A.x + Sx2A.y, SypA = Sy2A.x + Sy2A.y;
    const float SxpB = Sx2B.x + Sx2B.y, SypB = Sy2B.x + Sy2B.y;
    const float c0pA = -SxpA * 0.3125f;
    const float rlnA = fmaxf(yA - yubA, 0.f) - fmaxf(ylbA - yA, 0.f);
    const float c2pA = rlnA - SypA * (1.0f/6.0f);
    const float c0ddA = xddA * ga1A, c0dA = xdA * gv1A;
    const float c2ddA = yddA * ga1A, c2dA = ydA * gv1A;
    const float c0pB = -SxpB * 0.3125f;
    const float rlnB = fmaxf(yB - yubB, 0.f) - fmaxf(ylbB - yB, 0.f);
    const float c2pB = rlnB - SypB * (1.0f/6.0f);
    const float c0ddB = xddB * ga1B, c0dB = xdB * gv1B;
    const float c2ddB = yddB * ga1B, c2dB = ydB * gv1B;

    // ---- residual back-projection into LDS, both problems ----
    {
      const f32x2 A0A = f32x2{c0ddA, c0ddA}, D0A = f32x2{c0dA, c0dA}, Q0A = f32x2{c0pA, c0pA};
      const f32x2 A2A = f32x2{c2ddA, c2ddA}, D2A = f32x2{c2dA, c2dA}, Q2A = f32x2{c2pA, c2pA};
      const f32x2 A0B = f32x2{c0ddB, c0ddB}, D0B = f32x2{c0dB, c0dB}, Q0B = f32x2{c0pB, c0pB};
      const f32x2 A2B = f32x2{c2ddB, c2ddB}, D2B = f32x2{c2dB, c2dB}, Q2B = f32x2{c2pB, c2pB};
      float* colA = redA + tid;
      float* colB = redB + tid;
      #pragma unroll
      for (int j2 = 0; j2 < 8; ++j2) {
        const f32x2 vxA = pfma(A0A, Pddr2[j2], pfma(D0A, Pdr2[j2], Q0A * Pr2[j2]));
        const f32x2 vyA = pfma(A2A, Pddr2[j2], pfma(D2A, Pdr2[j2], Q2A * Pr2[j2]));
        const f32x2 vxB = pfma(A0B, Pddr2[j2], pfma(D0B, Pdr2[j2], Q0B * Pr2[j2]));
        const f32x2 vyB = pfma(A2B, Pddr2[j2], pfma(D2B, Pdr2[j2], Q2B * Pr2[j2]));
        colA[(2*j2  )*RSTRIDE]  = vxA.x;
        colA[(2*j2+1)*RSTRIDE]  = vxA.y;
        colA[(16+2*j2)*RSTRIDE] = vyA.x;
        colA[(17+2*j2)*RSTRIDE] = vyA.y;
        colB[(2*j2  )*RSTRIDE]  = vxB.x;
        colB[(2*j2+1)*RSTRIDE]  = vxB.y;
        colB[(16+2*j2)*RSTRIDE] = vyB.x;
        colB[(17+2*j2)*RSTRIDE] = vyB.y;
      }
    }
    __syncthreads();                                   // bar 1: red ready

    // ---- reduce both problems (independent LDS chains overlap) ----
    float hA, hB;
    {
      const int chunk = (tid >> 5) * 32;
      const float* rbA = redA + r32*RSTRIDE + chunk;
      const float* rbB = redB + r32*RSTRIDE + chunk;
      f32x2 sA1{}, sA2{}, sB1{}, sB2{};
      #pragma unroll
      for (int mch = 0; mch < 8; ++mch) {
        F4 ta, tb;
        ta.v = *reinterpret_cast<const float4*>(rbA + 4*mch);
        tb.v = *reinterpret_cast<const float4*>(rbB + 4*mch);
        sA1 += f32x2{ta.f[0], ta.f[1]};
        sA2 += f32x2{ta.f[2], ta.f[3]};
        sB1 += f32x2{tb.f[0], tb.f[1]};
        sB2 += f32x2{tb.f[2], tb.f[3]};
      }
      const f32x2 sAv = sA1 + sA2;
      const f32x2 sBv = sB1 + sB2;
      float sA = sAv.x + sAv.y;
      float sB = sBv.x + sBv.y;
      sA += __shfl_xor(sA, 32);
      sB += __shfl_xor(sB, 32);
      if (lane < 32) { pLA[wv][lane] = sA; pLB[wv][lane] = sB; }
      __syncthreads();                                 // bar 2: partials ready

      const float SA = sA + pLA[wv ^ 1][r32];
      const float SB = sB + pLB[wv ^ 1][r32];
      lamA -= SA;
      lamB -= SB;
      hA = lamA - SA;
      hB = lamB - SB;
      if (lane < 32) { hLwA[wv][lane] = hA; hLwB[wv][lane] = hB; }
    }

    // ---- fused solves (M/MG row loads shared between A and B) ----
    {
      f32x2 accA{}, accB{};
      #pragma unroll
      for (int q = 0; q < 4; ++q) {
        F4 m4, g4, hA4, cA4, hB4, cB4;
        m4.v  = *reinterpret_cast<const float4*>(Mrow  + 4*q);
        g4.v  = *reinterpret_cast<const float4*>(MGrow + 4*q);
        hA4.v = *reinterpret_cast<const float4*>(&hLwA[wv][side*16 + 4*q]);
        cA4.v = *reinterpret_cast<const float4*>(&cLwA[wv][side*16 + 4*q]);
        hB4.v = *reinterpret_cast<const float4*>(&hLwB[wv][side*16 + 4*q]);
        cB4.v = *reinterpret_cast<const float4*>(&cLwB[wv][side*16 + 4*q]);
        const f32x2 m01 = f32x2{m4.f[0], m4.f[1]}, m23 = f32x2{m4.f[2], m4.f[3]};
        const f32x2 g01 = f32x2{g4.f[0], g4.f[1]}, g23 = f32x2{g4.f[2], g4.f[3]};
        accA = pfma(m01, f32x2{hA4.f[0], hA4.f[1]}, accA);
        accA = pfma(g01, f32x2{cA4.f[0], cA4.f[1]}, accA);
        accA = pfma(m23, f32x2{hA4.f[2], hA4.f[3]}, accA);
        accA = pfma(g23, f32x2{cA4.f[2], cA4.f[3]}, accA);
        accB = pfma(m01, f32x2{hB4.f[0], hB4.f[1]}, accB);
        accB = pfma(g01, f32x2{cB4.f[0], cB4.f[1]}, accB);
        accB = pfma(m23, f32x2{hB4.f[2], hB4.f[3]}, accB);
        accB = pfma(g23, f32x2{cB4.f[2], cB4.f[3]}, accB);
      }
      mycA = constvA + accA.x + accA.y;
      mycB = constvB + accB.x + accB.y;
      if (lane < 32) { cLwA[wv][lane] = mycA; cLwB[wv][lane] = mycB; }
    }
  }

  if (tid < 32)      out[b0*32 + tid]        = mycA;
  else if (tid < 64) out[b1*32 + (tid - 32)] = mycB;
}

extern "C" void kernel_launch(void* const* d_in, const int* in_sizes, int n_in,
                              void* d_out, int out_size, void* d_ws, size_t ws_size,
                              hipStream_t stream) {
  const float* P    = (const float*)d_in[0];
  const float* Pd   = (const float*)d_in[1];
  const float* Pdd  = (const float*)d_in[2];
  const float* init = (const float*)d_in[3];
  const float* fin  = (const float*)d_in[4];
  const float* cobs = (const float*)d_in[5];
  const float* vobs = (const float*)d_in[6];
  const float* yub  = (const float*)d_in[7];
  const float* ylb  = (const float*)d_in[8];
  const float* lamx = (const float*)d_in[9];
  const float* lamy = (const float*)d_in[10];
  const float* cxp  = (const float*)d_in[11];
  const float* cyp  = (const float*)d_in[12];
  float* ws  = (float*)d_ws;
  float* o   = (float*)d_out;

  planner_setup<<<dim3(4), dim3(64), 0, stream>>>(P, Pd, Pdd, ws);
  planner_main<<<dim3(NBATCH/2), dim3(128), 0, stream>>>(
      P, Pd, Pdd, init, fin, cobs, vobs, yub, ylb, lamx, lamy, cxp, cyp, ws, o);
}

// Round 9
// 254.052 us; speedup vs baseline: 1.0281x; 1.0281x over previous
//
#include <hip/hip_runtime.h>
#include <math.h>

#define NBATCH 4096
#define TNUM   128
#define NOBSC  10
#define MAXIT  30

// ws layout (floats)
#define WS_MX   0      // 16x16
#define WS_MY   256    // 16x16
#define WS_MGX  512    // 16x16  (Mx*Gx)
#define WS_MGY  768    // 16x16  (My*Gy)
#define WS_NX   1024   // 16x8
#define WS_NY   1152   // 16x9
#define WS_NX0  1296   // 16x8
#define WS_NY0  1424   // 16x9
// total 1568 floats

#define RS 36          // red row stride (16 quad-rows x 32 cols + pad)

typedef float f32x2 __attribute__((ext_vector_type(2)));
union F4 { float4 v; float f[4]; };

__device__ __forceinline__ f32x2 pfma(f32x2 a, f32x2 b, f32x2 c) {
  return __builtin_elementwise_fma(a, b, c);
}

// quad-lane (4 consecutive lanes) all-reduce sum via DPP (VALU pipe, no LDS)
__device__ __forceinline__ float qsum(float v) {
  float s = v + __int_as_float(__builtin_amdgcn_update_dpp(
      0, __float_as_int(v), 0xB1, 0xF, 0xF, true));   // quad_perm [1,0,3,2] = xor1
  s = s + __int_as_float(__builtin_amdgcn_update_dpp(
      0, __float_as_int(s), 0x4E, 0xF, 0xF, true));   // quad_perm [2,3,0,1] = xor2
  return s;
}

// ---------------- setup kernel: build + invert KKT matrices (fp64 GJ) -------
__global__ __launch_bounds__(64) void planner_setup(
    const float* __restrict__ P, const float* __restrict__ Pd, const float* __restrict__ Pdd,
    float* __restrict__ ws)
{
  const int mid = blockIdx.x;   // 0: (cost_sm,Ax)->Nx0  1: (cost_sm,Ay)->Ny0
                                // 2: (cost_x,Ax)->Mx,Nx,MGx 3: (cost_y,Ay)->My,Ny,MGy
  const int tid = threadIdx.x;
  __shared__ double C[16][16];
  __shared__ double G[16][16];
  __shared__ double Ae[9][16];
  __shared__ double aug[25][50];
  __shared__ int pivs;

  const bool isY = (mid & 1);
  const int  m   = isY ? 9 : 8;
  const int  n   = 16 + m;
  const int  w   = 2 * n;

  for (int e = tid; e < 256; e += 64) {
    const int j = e >> 4, kk = e & 15;
    double gdd = 0.0, gd = 0.0, g0 = 0.0;
    for (int t = 0; t < TNUM; ++t) {
      gdd += (double)Pdd[t*16+j] * (double)Pdd[t*16+kk];
      gd  += (double)Pd [t*16+j] * (double)Pd [t*16+kk];
      g0  += (double)P  [t*16+j] * (double)P  [t*16+kk];
    }
    const double cs = 100.0 * (gdd + ((j == kk) ? 0.1 : 0.0));
    const double g  = gdd + gd + (isY ? 12.0 : 10.0) * g0;
    G[j][kk] = g;
    C[j][kk] = (mid >= 2) ? (cs + g) : cs;
  }
  if (tid < 16) {
    const int j = tid;
    Ae[0][j] = (double)P  [0*16+j];
    Ae[1][j] = (double)Pd [0*16+j];
    Ae[2][j] = (double)Pdd[0*16+j];
    if (!isY) {
      Ae[3][j] = (double)Pd[127*16+j];
      for (int r = 4; r < 8; ++r) Ae[r][j] = (j == r) ? 1.0 : 0.0;
    } else {
      Ae[3][j] = (double)P [127*16+j];
      Ae[4][j] = (double)Pd[127*16+j];
      for (int r = 5; r < 9; ++r) Ae[r][j] = (j == (r-1)) ? 1.0 : 0.0;
    }
  }
  __syncthreads();

  for (int e = tid; e < n * w; e += 64) {
    const int r = e / w, c = e % w;
    double val;
    if (c < n) {
      if (r < 16) val = (c < 16) ? C[r][c] : Ae[c-16][r];
      else        val = (c < 16) ? Ae[r-16][c] : 0.0;
    } else {
      val = ((c - n) == r) ? 1.0 : 0.0;
    }
    aug[r][c] = val;
  }
  __syncthreads();

  for (int kk = 0; kk < n; ++kk) {
    if (tid == 0) {
      int p = kk; double best = fabs(aug[kk][kk]);
      for (int r = kk+1; r < n; ++r) { double a = fabs(aug[r][kk]); if (a > best) { best = a; p = r; } }
      pivs = p;
    }
    __syncthreads();
    const int p = pivs;
    if (p != kk) {
      for (int c = tid; c < w; c += 64) { double t = aug[kk][c]; aug[kk][c] = aug[p][c]; aug[p][c] = t; }
    }
    __syncthreads();
    const double ipiv = 1.0 / aug[kk][kk];
    for (int c = tid; c < w; c += 64) aug[kk][c] *= ipiv;
    __syncthreads();
    for (int r = tid; r < n; r += 64) {
      if (r != kk) {
        const double f = aug[r][kk];
        for (int c = kk; c < w; ++c) aug[r][c] -= f * aug[kk][c];
      }
    }
    __syncthreads();
  }

  if (mid == 0) {
    for (int e = tid; e < 16*8; e += 64) ws[WS_NX0 + e] = (float)aug[e >> 3][n + 16 + (e & 7)];
  } else if (mid == 1) {
    for (int e = tid; e < 16*9; e += 64) ws[WS_NY0 + e] = (float)aug[e / 9][n + 16 + (e % 9)];
  } else if (mid == 2) {
    for (int e = tid; e < 256;  e += 64) ws[WS_MX + e] = (float)aug[e >> 4][n + (e & 15)];
    for (int e = tid; e < 16*8; e += 64) ws[WS_NX + e] = (float)aug[e >> 3][n + 16 + (e & 7)];
  } else {
    for (int e = tid; e < 256;  e += 64) ws[WS_MY + e] = (float)aug[e >> 4][n + (e & 15)];
    for (int e = tid; e < 16*9; e += 64) ws[WS_NY + e] = (float)aug[e / 9][n + 16 + (e % 9)];
  }

  if (mid >= 2) {
    for (int e = tid; e < 256; e += 64) {
      const int j = e >> 4, kk = e & 15;
      double s = 0.0;
      for (int mm = 0; mm < 16; ++mm) s += aug[j][n + mm] * G[mm][kk];
      ws[(mid == 2 ? WS_MGX : WS_MGY) + e] = (float)s;
    }
  }
}

// ---- main kernel: ONE wave (64 threads) per problem, 2 timesteps/thread ----
__global__ __launch_bounds__(64) void planner_main(
    const float* __restrict__ P, const float* __restrict__ Pd, const float* __restrict__ Pdd,
    const float* __restrict__ init_state, const float* __restrict__ fin_state,
    const float* __restrict__ cobs, const float* __restrict__ vobs,
    const float* __restrict__ yub_g, const float* __restrict__ ylb_g,
    const float* __restrict__ lamx_g, const float* __restrict__ lamy_g,
    const float* __restrict__ cxp_g, const float* __restrict__ cyp_g,
    const float* __restrict__ ws, float* __restrict__ out)
{
  const int b    = blockIdx.x;
  const int tid  = threadIdx.x;        // timesteps t0 = tid, t1 = tid + 64
  const int o32  = tid & 31;           // reduction row owned (dup over cc)
  const int cc   = tid >> 5;
  const int rr   = tid & 15;           // solve row
  const int side = (tid >> 4) & 1;     // 0 = x-side, 1 = y-side
  const int q4   = tid >> 2;           // quad index (0..15)
  const int k    = tid & 3;            // lane-in-quad

  __shared__ alignas(16) float red[16*RS];  // [quad][o], 2.3 KB
  __shared__ alignas(16) float cL[32];
  __shared__ alignas(16) float hL[32];

  // basis rows for both timesteps (j-pair packed)
  f32x2 Pr2[2][8], Pdr2[2][8], Pddr2[2][8];
  #pragma unroll
  for (int u = 0; u < 2; ++u) {
    const int t = tid + 64*u;
    #pragma unroll
    for (int q = 0; q < 4; ++q) {
      F4 a, bb, ce;
      a.v  = *reinterpret_cast<const float4*>(P   + t*16 + 4*q);
      bb.v = *reinterpret_cast<const float4*>(Pd  + t*16 + 4*q);
      ce.v = *reinterpret_cast<const float4*>(Pdd + t*16 + 4*q);
      Pr2  [u][2*q+0] = f32x2{a.f[0],  a.f[1]};  Pr2  [u][2*q+1] = f32x2{a.f[2],  a.f[3]};
      Pdr2 [u][2*q+0] = f32x2{bb.f[0], bb.f[1]}; Pdr2 [u][2*q+1] = f32x2{bb.f[2], bb.f[3]};
      Pddr2[u][2*q+0] = f32x2{ce.f[0], ce.f[1]}; Pddr2[u][2*q+1] = f32x2{ce.f[2], ce.f[3]};
    }
  }

  // pre-scaled obstacle trajectories at both timesteps (obstacle-pair packed)
  f32x2 xot0[5], yot0[5], xot1[5], yot1[5];
  {
    const float tt0 = (float)tid        * (10.0f/127.0f);
    const float tt1 = (float)(tid + 64) * (10.0f/127.0f);
    #pragma unroll
    for (int o5 = 0; o5 < 5; ++o5) {
      const int o = 2*o5;
      const float xo0 = cobs[b*20+o],    xo1 = cobs[b*20+o+1];
      const float yo0 = cobs[b*20+10+o], yo1 = cobs[b*20+11+o];
      const float vx0 = vobs[b*20+o],    vx1 = vobs[b*20+o+1];
      const float vy0 = vobs[b*20+10+o], vy1 = vobs[b*20+11+o];
      xot0[o5] = f32x2{3.2f*fmaf(vx0,tt0,xo0), 3.2f*fmaf(vx1,tt0,xo1)};
      yot0[o5] = f32x2{6.0f*fmaf(vy0,tt0,yo0), 6.0f*fmaf(vy1,tt0,yo1)};
      xot1[o5] = f32x2{3.2f*fmaf(vx0,tt1,xo0), 3.2f*fmaf(vx1,tt1,xo1)};
      yot1[o5] = f32x2{6.0f*fmaf(vy0,tt1,yo0), 6.0f*fmaf(vy1,tt1,yo1)};
    }
  }
  const float yub = yub_g[b], ylb = ylb_g[b];

  // lambda carry for owned reduction row (dup across cc)
  float lam = (o32 < 16) ? lamx_g[b*16 + o32] : lamy_g[b*16 + (o32 - 16)];

  // per-lane solve-row setup: const term, initial c (row rr, side)
  float constv, myc;
  {
    float beq[9];
    const float vi  = init_state[b*4+2];
    const float psi = init_state[b*4+3];
    if (side == 0) {
      beq[0] = init_state[b*4+0];
      beq[1] = vi * cosf(psi);
      beq[2] = 0.f;
      beq[3] = fin_state[b*3+0];
      #pragma unroll
      for (int i2 = 0; i2 < 4; ++i2) beq[4+i2] = cxp_g[b*4+i2];
      beq[8] = 0.f;                      // pad: multiplies in-bounds junk * 0
    } else {
      beq[0] = init_state[b*4+1];
      beq[1] = vi * sinf(psi);
      beq[2] = 0.f;
      beq[3] = fin_state[b*3+1];
      beq[4] = 0.f;
      #pragma unroll
      for (int i2 = 0; i2 < 4; ++i2) beq[5+i2] = cyp_g[b*4+i2];
    }
    const int nstr = side ? 9 : 8;
    const float* Np  = ws + (side ? WS_NY  : WS_NX ) + rr*nstr;
    const float* N0p = ws + (side ? WS_NY0 : WS_NX0) + rr*nstr;
    float cv = 0.f, c0 = 0.f;
    #pragma unroll
    for (int mm = 0; mm < 9; ++mm) {
      const float bm = beq[mm];
      cv = fmaf(Np[mm],  bm, cv);
      c0 = fmaf(N0p[mm], bm, c0);
    }
    constv = cv;
    myc    = c0;
  }
  if (tid < 32) cL[tid] = myc;           // same-wave DS ordering

  const float* Mrow  = ws + (side ? WS_MY  : WS_MX ) + rr*16;
  const float* MGrow = ws + (side ? WS_MGY : WS_MGX) + rr*16;
  const bool  kb2 = (k & 2) != 0;
  const int   k1  = k & 1;

  #pragma unroll 1
  for (int it = 0; it < MAXIT; ++it) {
    __builtin_amdgcn_wave_barrier();
    // ---- forward matvecs at t0 and t1 ----
    f32x2 xv0{},yv0{},xdv0{},ydv0{},xddv0{},yddv0{};
    f32x2 xv1{},yv1{},xdv1{},ydv1{},xddv1{},yddv1{};
    #pragma unroll
    for (int q = 0; q < 4; ++q) {
      F4 cx4, cy4;
      cx4.v = *reinterpret_cast<const float4*>(&cL[4*q]);
      cy4.v = *reinterpret_cast<const float4*>(&cL[16 + 4*q]);
      const f32x2 c01 = f32x2{cx4.f[0], cx4.f[1]}, c23 = f32x2{cx4.f[2], cx4.f[3]};
      const f32x2 d01 = f32x2{cy4.f[0], cy4.f[1]}, d23 = f32x2{cy4.f[2], cy4.f[3]};
      xv0   = pfma(Pr2  [0][2*q], c01, xv0);   xv0   = pfma(Pr2  [0][2*q+1], c23, xv0);
      yv0   = pfma(Pr2  [0][2*q], d01, yv0);   yv0   = pfma(Pr2  [0][2*q+1], d23, yv0);
      xdv0  = pfma(Pdr2 [0][2*q], c01, xdv0);  xdv0  = pfma(Pdr2 [0][2*q+1], c23, xdv0);
      ydv0  = pfma(Pdr2 [0][2*q], d01, ydv0);  ydv0  = pfma(Pdr2 [0][2*q+1], d23, ydv0);
      xddv0 = pfma(Pddr2[0][2*q], c01, xddv0); xddv0 = pfma(Pddr2[0][2*q+1], c23, xddv0);
      yddv0 = pfma(Pddr2[0][2*q], d01, yddv0); yddv0 = pfma(Pddr2[0][2*q+1], d23, yddv0);
      xv1   = pfma(Pr2  [1][2*q], c01, xv1);   xv1   = pfma(Pr2  [1][2*q+1], c23, xv1);
      yv1   = pfma(Pr2  [1][2*q], d01, yv1);   yv1   = pfma(Pr2  [1][2*q+1], d23, yv1);
      xdv1  = pfma(Pdr2 [1][2*q], c01, xdv1);  xdv1  = pfma(Pdr2 [1][2*q+1], c23, xdv1);
      ydv1  = pfma(Pdr2 [1][2*q], d01, ydv1);  ydv1  = pfma(Pdr2 [1][2*q+1], d23, ydv1);
      xddv1 = pfma(Pddr2[1][2*q], c01, xddv1); xddv1 = pfma(Pddr2[1][2*q+1], c23, xddv1);
      yddv1 = pfma(Pddr2[1][2*q], d01, yddv1); yddv1 = pfma(Pddr2[1][2*q+1], d23, yddv1);
    }
    const float x0=xv0.x+xv0.y, y0=yv0.x+yv0.y, xd0=xdv0.x+xdv0.y, yd0=ydv0.x+ydv0.y;
    const float xdd0=xddv0.x+xddv0.y, ydd0=yddv0.x+yddv0.y;
    const float x1=xv1.x+xv1.y, y1=yv1.x+yv1.y, xd1=xdv1.x+xdv1.y, yd1=ydv1.x+ydv1.y;
    const float xdd1=xddv1.x+xddv1.y, ydd1=yddv1.x+yddv1.y;

    // ---- projections ----
    const float ria0 = rsqrtf(fmaxf(fmaf(xdd0,xdd0,ydd0*ydd0), 1e-36f));
    const float ga10 = 1.0f - fminf(1.0f, 18.0f*ria0);
    const float riv0 = rsqrtf(fmaxf(fmaf(xd0,xd0,yd0*yd0), 1e-36f));
    const float gv10 = 1.0f - fminf(fmaxf(1.0f, 0.1f*riv0), 30.0f*riv0);
    const float ria1 = rsqrtf(fmaxf(fmaf(xdd1,xdd1,ydd1*ydd1), 1e-36f));
    const float ga11 = 1.0f - fminf(1.0f, 18.0f*ria1);
    const float riv1 = rsqrtf(fmaxf(fmaf(xd1,xd1,yd1*yd1), 1e-36f));
    const float gv11 = 1.0f - fminf(fmaxf(1.0f, 0.1f*riv1), 30.0f*riv1);

    // ---- obstacles ----
    f32x2 Sx0{}, Sy0{}, Sx1{}, Sy1{};
    {
      const f32x2 xb0 = f32x2{3.2f*x0, 3.2f*x0}, yb0 = f32x2{6.0f*y0, 6.0f*y0};
      const f32x2 xb1 = f32x2{3.2f*x1, 3.2f*x1}, yb1 = f32x2{6.0f*y1, 6.0f*y1};
      #pragma unroll
      for (int o5 = 0; o5 < 5; ++o5) {
        const f32x2 bw0 = xb0 - xot0[o5], aw0 = yb0 - yot0[o5];
        const f32x2 bw1 = xb1 - xot1[o5], aw1 = yb1 - yot1[o5];
        const f32x2 r20 = pfma(bw0,bw0,aw0*aw0);
        const f32x2 r21 = pfma(bw1,bw1,aw1*aw1);
        const f32x2 ee0 = f32x2{
          fmaxf(fmaf(19.2f, rsqrtf(fmaxf(r20.x,1e-36f)), -1.0f), 0.f),
          fmaxf(fmaf(19.2f, rsqrtf(fmaxf(r20.y,1e-36f)), -1.0f), 0.f)};
        const f32x2 ee1 = f32x2{
          fmaxf(fmaf(19.2f, rsqrtf(fmaxf(r21.x,1e-36f)), -1.0f), 0.f),
          fmaxf(fmaf(19.2f, rsqrtf(fmaxf(r21.y,1e-36f)), -1.0f), 0.f)};
        Sx0 = pfma(ee0, bw0, Sx0);  Sy0 = pfma(ee0, aw0, Sy0);
        Sx1 = pfma(ee1, bw1, Sx1);  Sy1 = pfma(ee1, aw1, Sy1);
      }
    }
    const float c0p0 = -(Sx0.x+Sx0.y)*0.3125f;
    const float rln0 = fmaxf(y0-yub,0.f) - fmaxf(ylb-y0,0.f);
    const float c2p0 = rln0 - (Sy0.x+Sy0.y)*(1.0f/6.0f);
    const float c0dd0 = xdd0*ga10, c0d0 = xd0*gv10;
    const float c2dd0 = ydd0*ga10, c2d0 = yd0*gv10;
    const float c0p1 = -(Sx1.x+Sx1.y)*0.3125f;
    const float rln1 = fmaxf(y1-yub,0.f) - fmaxf(ylb-y1,0.f);
    const float c2p1 = rln1 - (Sy1.x+Sy1.y)*(1.0f/6.0f);
    const float c0dd1 = xdd1*ga11, c0d1 = xd1*gv11;
    const float c2dd1 = ydd1*ga11, c2d1 = yd1*gv11;

    // ---- back-projection (pre-summed over own 2 t's) + quad DPP reduce ----
    float outv[8];
    #pragma unroll
    for (int s2 = 0; s2 < 8; ++s2) outv[s2] = 0.f;
    {
      const f32x2 A00{c0dd0,c0dd0}, D00{c0d0,c0d0}, Q00{c0p0,c0p0};
      const f32x2 A20{c2dd0,c2dd0}, D20{c2d0,c2d0}, Q20{c2p0,c2p0};
      const f32x2 A01{c0dd1,c0dd1}, D01{c0d1,c0d1}, Q01{c0p1,c0p1};
      const f32x2 A21{c2dd1,c2dd1}, D21{c2d1,c2d1}, Q21{c2p1,c2p1};
      #pragma unroll
      for (int j2 = 0; j2 < 8; ++j2) {
        f32x2 vx = pfma(A00, Pddr2[0][j2], pfma(D00, Pdr2[0][j2], Q00*Pr2[0][j2]));
        vx = pfma(A01, Pddr2[1][j2], pfma(D01, Pdr2[1][j2], pfma(Q01, Pr2[1][j2], vx)));
        f32x2 vy = pfma(A20, Pddr2[0][j2], pfma(D20, Pdr2[0][j2], Q20*Pr2[0][j2]));
        vy = pfma(A21, Pddr2[1][j2], pfma(D21, Pdr2[1][j2], pfma(Q21, Pr2[1][j2], vy)));
        // quad sums (each covers 8 timesteps)
        const float qx0 = qsum(vx.x), qx1 = qsum(vx.y);
        const float qy0 = qsum(vy.x), qy1 = qsum(vy.y);
        // lane k of each quad keeps o-chunk [8k, 8k+8)
        const float s0 = kb2 ? qy0 : qx0;
        const float s1 = kb2 ? qy1 : qx1;
        const bool match = (k1 == (j2 >> 2));
        const int  sb = 2*(j2 & 3);
        outv[sb]   = match ? s0 : outv[sb];
        outv[sb+1] = match ? s1 : outv[sb+1];
      }
    }
    __builtin_amdgcn_wave_barrier();
    {
      float* wr = red + q4*RS + 8*k;
      *reinterpret_cast<float4*>(wr)     = float4{outv[0],outv[1],outv[2],outv[3]};
      *reinterpret_cast<float4*>(wr + 4) = float4{outv[4],outv[5],outv[6],outv[7]};
    }
    __builtin_amdgcn_wave_barrier();

    // ---- reduce 16 quad-rows for owned column o32 ----
    float h;
    {
      const float* rd = red + (cc*8)*RS + o32;
      float s = 0.f;
      #pragma unroll
      for (int i = 0; i < 8; ++i) s += rd[i*RS];
      s += __shfl_xor(s, 32);
      lam -= s;
      h = lam - s;                         // lam_old - 2S
    }
    __builtin_amdgcn_wave_barrier();
    if (tid < 32) hL[tid] = h;
    __builtin_amdgcn_wave_barrier();

    // ---- fused solve: c' = MG*c + M*h + const ----
    {
      f32x2 accv{};
      #pragma unroll
      for (int q = 0; q < 4; ++q) {
        F4 m4, g4, h4, c4;
        m4.v = *reinterpret_cast<const float4*>(Mrow  + 4*q);
        g4.v = *reinterpret_cast<const float4*>(MGrow + 4*q);
        h4.v = *reinterpret_cast<const float4*>(&hL[side*16 + 4*q]);
        c4.v = *reinterpret_cast<const float4*>(&cL[side*16 + 4*q]);
        accv = pfma(f32x2{m4.f[0],m4.f[1]}, f32x2{h4.f[0],h4.f[1]}, accv);
        accv = pfma(f32x2{g4.f[0],g4.f[1]}, f32x2{c4.f[0],c4.f[1]}, accv);
        accv = pfma(f32x2{m4.f[2],m4.f[3]}, f32x2{h4.f[2],h4.f[3]}, accv);
        accv = pfma(f32x2{g4.f[2],g4.f[3]}, f32x2{c4.f[2],c4.f[3]}, accv);
      }
      myc = constv + accv.x + accv.y;
    }
    __builtin_amdgcn_wave_barrier();
    if (tid < 32) cL[tid] = myc;           // next iter reads (same-wave order)
  }

  if (tid < 32) out[b*32 + tid] = myc;
}

extern "C" void kernel_launch(void* const* d_in, const int* in_sizes, int n_in,
                              void* d_out, int out_size, void* d_ws, size_t ws_size,
                              hipStream_t stream) {
  const float* P    = (const float*)d_in[0];
  const float* Pd   = (const float*)d_in[1];
  const float* Pdd  = (const float*)d_in[2];
  const float* init = (const float*)d_in[3];
  const float* fin  = (const float*)d_in[4];
  const float* cobs = (const float*)d_in[5];
  const float* vobs = (const float*)d_in[6];
  const float* yub  = (const float*)d_in[7];
  const float* ylb  = (const float*)d_in[8];
  const float* lamx = (const float*)d_in[9];
  const float* lamy = (const float*)d_in[10];
  const float* cxp  = (const float*)d_in[11];
  const float* cyp  = (const float*)d_in[12];
  float* ws  = (float*)d_ws;
  float* o   = (float*)d_out;

  planner_setup<<<dim3(4), dim3(64), 0, stream>>>(P, Pd, Pdd, ws);
  planner_main<<<dim3(NBATCH), dim3(64), 0, stream>>>(
      P, Pd, Pdd, init, fin, cobs, vobs, yub, ylb, lamx, lamy, cxp, cyp, ws, o);
}